// Round 1
// baseline (64.142 us; speedup 1.0000x reference)
//
#include <hip/hip_runtime.h>
#include <hip/hip_bf16.h>
#include <stdint.h>

#define NB 8
#define LQ 256
#define LK 512
#define DQ 256
#define DV 256
#define NH 64
// 2*log2(e): folded into projections so tanh(x) = 1 - 2/(1+exp2(SCALE*x_sum))
#define SCALE 2.8853900817779268f
#define L2E 1.4426950408889634f

#define QP_ELEMS (NB*LQ*NH)     // 131072 f32
#define KPT_ELEMS (NB*NH*LK)    // 262144 f32

extern "C" __device__ float __ocml_exp2_f32(float);
static __device__ __forceinline__ float fexp2(float x) {
#if __has_builtin(__builtin_amdgcn_exp2f)
  return __builtin_amdgcn_exp2f(x);
#else
  return __ocml_exp2_f32(x);
#endif
}
static __device__ __forceinline__ float frcp(float x) {
  return __builtin_amdgcn_rcpf(x);
}
static __device__ __forceinline__ uint16_t f2bf(float f) {
  uint32_t u = __float_as_uint(f);
  uint32_t r = (u + 0x7FFFu + ((u >> 16) & 1u)) >> 16;  // RNE
  return (uint16_t)r;
}

// blocks 0..63:   q-projection  (32 row-tiles x 2 h-halves)  -> qp[row][h] (scaled)
// blocks 64..191: k-projection  (64 row-tiles x 2 h-halves)  -> kpT[b][h][kj] (scaled, transposed)
// blocks 192..255: values f32 -> bf16
__global__ __launch_bounds__(256) void proj_kernel(
    const float* __restrict__ queries, const float* __restrict__ keys,
    const float* __restrict__ values,
    const float* __restrict__ Wq, const float* __restrict__ Wk,
    float* __restrict__ qp, float* __restrict__ kpT, uint16_t* __restrict__ vbf)
{
  __shared__ float Wt[256][36];  // [d][h_local], pad 36 to break store bank conflicts
  const int blk = blockIdx.x;
  const int t = threadIdx.x;

  if (blk >= 192) {
    // convert values (1,048,576 f32) to bf16; 64 blocks * 256 thr * 16 * float4
    int base = (blk - 192) * 16384 + t * 4;
#pragma unroll
    for (int it = 0; it < 16; ++it) {
      int idx = base + it * 1024;
      float4 v = *(const float4*)(values + idx);
      uint32_t lo = (uint32_t)f2bf(v.x) | ((uint32_t)f2bf(v.y) << 16);
      uint32_t hi = (uint32_t)f2bf(v.z) | ((uint32_t)f2bf(v.w) << 16);
      uint2 pk = {lo, hi};
      *(uint2*)(vbf + idx) = pk;
    }
    return;
  }

  const bool isQ = (blk < 64);
  const int sub = isQ ? blk : (blk - 64);
  const int tile = sub >> 1;
  const int hh = (sub & 1) * 32;
  const int rowbase = tile * 64;
  const float* __restrict__ X = isQ ? queries : keys;
  const float* __restrict__ W = isQ ? Wq : Wk;

  // stage W[hh..hh+31][0..255] transposed into Wt[d][hl]
#pragma unroll 4
  for (int it = 0; it < 32; ++it) {
    Wt[t][it] = W[(hh + it) * 256 + t];
  }
  __syncthreads();

  const int ty = t >> 4;          // 0..15 -> 4 rows each
  const int tx = t & 15;          // 0..15 -> 2 h each
  float acc[4][2];
#pragma unroll
  for (int i = 0; i < 4; ++i) { acc[i][0] = 0.f; acc[i][1] = 0.f; }

  const float* xr0 = X + (rowbase + ty * 4 + 0) * 256;
  const float* xr1 = X + (rowbase + ty * 4 + 1) * 256;
  const float* xr2 = X + (rowbase + ty * 4 + 2) * 256;
  const float* xr3 = X + (rowbase + ty * 4 + 3) * 256;

#pragma unroll 2
  for (int d4 = 0; d4 < 64; ++d4) {
    int d = d4 * 4;
    float4 x0 = *(const float4*)(xr0 + d);
    float4 x1 = *(const float4*)(xr1 + d);
    float4 x2 = *(const float4*)(xr2 + d);
    float4 x3 = *(const float4*)(xr3 + d);
    float2 w0 = *(float2*)&Wt[d + 0][tx * 2];
    float2 w1 = *(float2*)&Wt[d + 1][tx * 2];
    float2 w2 = *(float2*)&Wt[d + 2][tx * 2];
    float2 w3 = *(float2*)&Wt[d + 3][tx * 2];
#define STEP(XC, WD) \
    acc[0][0] = fmaf(x0.XC, WD.x, acc[0][0]); acc[0][1] = fmaf(x0.XC, WD.y, acc[0][1]); \
    acc[1][0] = fmaf(x1.XC, WD.x, acc[1][0]); acc[1][1] = fmaf(x1.XC, WD.y, acc[1][1]); \
    acc[2][0] = fmaf(x2.XC, WD.x, acc[2][0]); acc[2][1] = fmaf(x2.XC, WD.y, acc[2][1]); \
    acc[3][0] = fmaf(x3.XC, WD.x, acc[3][0]); acc[3][1] = fmaf(x3.XC, WD.y, acc[3][1]);
    STEP(x, w0) STEP(y, w1) STEP(z, w2) STEP(w, w3)
#undef STEP
  }

#pragma unroll
  for (int i = 0; i < 4; ++i) {
    int row = rowbase + ty * 4 + i;
#pragma unroll
    for (int j = 0; j < 2; ++j) {
      int h = hh + tx * 2 + j;
      float val = acc[i][j] * SCALE;
      if (isQ) {
        qp[row * 64 + h] = val;
      } else {
        int b = row >> 9, kj = row & 511;
        kpT[(b * 64 + h) * 512 + kj] = val;
      }
    }
  }
}

// 512 WGs: wg -> b = wg&7 (balance random valid_lens across CUs), qb = wg>>3.
// 4 waves/WG, 1 q-row per wave. Per 64-k tile: stage kT(f32,16KB)+V(bf16,32KB),
// lane=k scores -> wave online softmax -> lane=d PV accumulate.
__global__ __launch_bounds__(256, 2) void attn_kernel(
    const float* __restrict__ qp, const float* __restrict__ kpT,
    const uint16_t* __restrict__ vbf, const float* __restrict__ w_v,
    const int* __restrict__ valid_lens, float* __restrict__ out)
{
  __shared__ float kTs[64][64];       // [h][kj] 16KB
  __shared__ uint32_t Vs[64][128];    // [kj][d pairs] bf16x2, 32KB
  __shared__ float p_lds[4][64];
  __shared__ float w2s[64];

  const int t = threadIdx.x;
  const int lane = t & 63;
  const int w = t >> 6;
  const int wg = blockIdx.x;
  const int b = wg & 7;
  const int qb = wg >> 3;
  const int qi = qb * 4 + w;

  if (t < 64) w2s[t] = -2.f * w_v[t];

  // W1 = sum(w_v) via wave butterfly
  float W1 = w_v[lane];
#pragma unroll
  for (int s = 32; s; s >>= 1) W1 += __shfl_xor(W1, s, 64);

  // q-row (pre-scaled) held in registers, uniform across the wave
  float qv[64];
  const float* qrow = qp + (b * LQ + qi) * 64;
#pragma unroll
  for (int i = 0; i < 16; ++i) {
    float4 v = *(const float4*)(qrow + i * 4);
    qv[i * 4 + 0] = v.x; qv[i * 4 + 1] = v.y; qv[i * 4 + 2] = v.z; qv[i * 4 + 3] = v.w;
  }

  const int vl = valid_lens[b];
  const int n = (vl > 0) ? vl : LK;     // vl==0 -> all -1e6 -> uniform softmax over all 512
  const int ntiles = (n + 63) >> 6;

  float m = -1e30f, l = 0.f;
  float acc0 = 0.f, acc1 = 0.f, acc2 = 0.f, acc3 = 0.f;

  const float* kpTb = kpT + b * 64 * 512;
  const uint16_t* vb = vbf + b * 512 * 256;

  for (int tile = 0; tile < ntiles; ++tile) {
    const int k0 = tile << 6;
    __syncthreads();
    {   // stage kT tile: thread -> h = t>>2, 16-float chunk c = t&3
      int h = t >> 2, c = t & 3;
      const float* src = kpTb + h * 512 + k0 + c * 16;
      float4* dst = (float4*)&kTs[h][c * 16];
#pragma unroll
      for (int j = 0; j < 4; ++j) dst[j] = *(const float4*)(src + j * 4);
    }
    {   // stage V tile (bf16): thread -> kj = t>>2, 128B segment seg = t&3
      int kj = t >> 2, seg = t & 3;
      const uint4* src = (const uint4*)((const uint32_t*)(vb + (size_t)(k0 + kj) * 256) + seg * 32);
      uint4* dst = (uint4*)&Vs[kj][seg * 32];
#pragma unroll
      for (int j = 0; j < 8; ++j) dst[j] = src[j];
    }
    __syncthreads();

    // ---- scores: lane = kj ----
    float r_acc = 0.f;
#pragma unroll
    for (int h = 0; h < 64; ++h) {
      float e = fexp2(qv[h] + kTs[h][lane]);     // exp2(2*log2e*(q+k)) = e^{2x}
      float r = frcp(1.f + e);                   // tanh = 1 - 2r
      r_acc = fmaf(w2s[h], r, r_acc);            // w2 = -2*w_v
    }
    float score;
    int kg = k0 + lane;
    if (vl == 0)       score = 0.f;
    else if (kg < n)   score = W1 + r_acc;
    else               score = -1e30f;

    // ---- online softmax (wave-wide) ----
    float mt = score;
#pragma unroll
    for (int s = 32; s; s >>= 1) mt = fmaxf(mt, __shfl_xor(mt, s, 64));
    float mnew = fmaxf(m, mt);
    float alpha = fexp2((m - mnew) * L2E);
    float p = fexp2((score - mnew) * L2E);
    m = mnew;
    float S = p;
#pragma unroll
    for (int s = 32; s; s >>= 1) S += __shfl_xor(S, s, 64);
    l = l * alpha + S;
    p_lds[w][lane] = p;   // same-wave handoff; compiler inserts lgkmcnt

    // ---- PV: lane = d-chunk (4 contiguous d), kj loop ----
    acc0 *= alpha; acc1 *= alpha; acc2 *= alpha; acc3 *= alpha;
#pragma unroll
    for (int kj4 = 0; kj4 < 16; ++kj4) {
      float4 pv = *(float4*)&p_lds[w][kj4 * 4];
#pragma unroll
      for (int jj = 0; jj < 4; ++jj) {
        int kj = kj4 * 4 + jj;
        uint2 vvv = *(uint2*)&Vs[kj][lane * 2];
        float pj = (jj == 0) ? pv.x : (jj == 1) ? pv.y : (jj == 2) ? pv.z : pv.w;
        float f0 = __uint_as_float(vvv.x << 16);
        float f1 = __uint_as_float(vvv.x & 0xFFFF0000u);
        float f2 = __uint_as_float(vvv.y << 16);
        float f3 = __uint_as_float(vvv.y & 0xFFFF0000u);
        acc0 = fmaf(pj, f0, acc0);
        acc1 = fmaf(pj, f1, acc1);
        acc2 = fmaf(pj, f2, acc2);
        acc3 = fmaf(pj, f3, acc3);
      }
    }
  }

  float inv = 1.f / l;
  float4 o = {acc0 * inv, acc1 * inv, acc2 * inv, acc3 * inv};
  *(float4*)(out + (size_t)(b * LQ + qi) * 256 + lane * 4) = o;
}

extern "C" void kernel_launch(void* const* d_in, const int* in_sizes, int n_in,
                              void* d_out, int out_size, void* d_ws, size_t ws_size,
                              hipStream_t stream) {
  const float* queries    = (const float*)d_in[0];
  const float* keys       = (const float*)d_in[1];
  const float* values     = (const float*)d_in[2];
  const int*   valid_lens = (const int*)d_in[3];
  const float* Wq         = (const float*)d_in[4];
  const float* Wk         = (const float*)d_in[5];
  const float* w_v        = (const float*)d_in[6];
  float* out = (float*)d_out;

  float* qp  = (float*)d_ws;                 // [2048][64]
  float* kpT = qp + QP_ELEMS;                // [8][64][512]
  uint16_t* vbf = (uint16_t*)(kpT + KPT_ELEMS);  // [8][512][256] bf16

  hipLaunchKernelGGL(proj_kernel, dim3(256), dim3(256), 0, stream,
                     queries, keys, values, Wq, Wk, qp, kpT, vbf);
  hipLaunchKernelGGL(attn_kernel, dim3(512), dim3(256), 0, stream,
                     qp, kpT, vbf, w_v, valid_lens, out);
}